// Round 12
// baseline (587.248 us; speedup 1.0000x reference)
//
#include <hip/hip_runtime.h>
#include <math.h>

#define NMAPS 16
#define DIN 512
#define DOUT 128
#define QD 64

typedef __attribute__((ext_vector_type(8))) short bf16x8;  // 8 bf16 (4 VGPR)
typedef __attribute__((ext_vector_type(4))) float f32x4;

// bf16 split helpers (RNE). x = bf2f(hi) + bf2f(lo) + O(2^-18 |x|).
__device__ __forceinline__ unsigned short f2bf(float x) {
  unsigned int u = __float_as_uint(x);
  return (unsigned short)((u + 0x7FFFu + ((u >> 16) & 1u)) >> 16);
}
__device__ __forceinline__ float bf2f(unsigned short h) {
  return __uint_as_float(((unsigned int)h) << 16);
}

// DPP helpers (VALU pipe).
__device__ __forceinline__ float qxor1(float x) {  // quad_perm {1,0,3,2}
  return __int_as_float(__builtin_amdgcn_update_dpp(
      0, __float_as_int(x), 0xB1, 0xF, 0xF, true));
}
__device__ __forceinline__ float qxor2(float x) {  // quad_perm {2,3,0,1}
  return __int_as_float(__builtin_amdgcn_update_dpp(
      0, __float_as_int(x), 0x4E, 0xF, 0xF, true));
}
__device__ __forceinline__ float hmirror(float x) {  // row_half_mirror: l -> 7-l
  return __int_as_float(__builtin_amdgcn_update_dpp(
      0, __float_as_int(x), 0x141, 0xF, 0xF, true));
}
// Butterfly sum over the 8-lane group, all on the VALU pipe (no LDS).
// Bitwise-identical to the previous swizzle version: after qxor1+qxor2 the
// value is quad-uniform, and half-mirror pairs each lane with the other quad.
__device__ __forceinline__ float groupSum8(float x) {
  x += qxor1(x);
  x += qxor2(x);
  x += hmirror(x);
  return x;
}

// slarfg sign convention (LAPACK) — unchanged since R4.
__device__ __forceinline__ void make_tau(float xn2, float alpha, float& tau,
                                         float& invs) {
  if (xn2 == 0.f) { tau = 0.f; invs = 0.f; }
  else {
    float mag = sqrtf(alpha * alpha + xn2);
    float beta = (alpha >= 0.f) ? -mag : mag;
    tau = (beta - alpha) / beta;
    invs = 1.f / (alpha - beta);
  }
}

// 4x4 blocked tree dot over 16 elements.
__device__ __forceinline__ float tree_dot16(const float (&x)[16],
                                            const float (&y)[16]) {
  float pp[4] = {0.f, 0.f, 0.f, 0.f};
#pragma unroll
  for (int q = 0; q < 4; ++q)
#pragma unroll
    for (int k = 0; k < 4; ++k)
      pp[q] = fmaf(x[4 * q + k], y[4 * q + k], pp[q]);
  return ((pp[0] + pp[1]) + pp[2]) + pp[3];
}

// Masked norm^2 over rows r = t+8k > piv, tree-reduced (prologue only).
__device__ __forceinline__ float tree_norm_gt16(const float (&a)[16],
                                                const int t, const int piv) {
  float ss[4] = {0.f, 0.f, 0.f, 0.f};
#pragma unroll
  for (int q = 0; q < 4; ++q)
#pragma unroll
    for (int k = 0; k < 4; ++k) {
      int kk = 4 * q + k;
      int r = t + 8 * kk;
      if (r > piv) ss[q] = fmaf(a[kk], a[kk], ss[q]);
    }
  return ((ss[0] + ss[1]) + ss[2]) + ss[3];
}

template <bool SCALE>
__device__ __forceinline__ void publish_col16(float (&a)[16], const int t,
                                              const int piv, const float invs,
                                              float* __restrict__ Vrow) {
#pragma unroll
  for (int k4 = 0; k4 < 4; ++k4) {
    float4 v4;
    float* vv = (float*)&v4;
#pragma unroll
    for (int e = 0; e < 4; ++e) {
      int k = 4 * k4 + e;
      int r = t + 8 * k;
      float nv;
      if (r > piv) {
        if (SCALE) a[k] *= invs;
        nv = a[k];
      } else nv = (r == piv) ? 1.f : 0.f;
      vv[e] = nv;
    }
    *(float4*)&Vrow[4 * k4] = v4;
  }
}

__device__ __forceinline__ void load_v16(float (&vr)[16],
                                         const float* __restrict__ Vrow) {
#pragma unroll
  for (int k4 = 0; k4 < 4; ++k4) {
    float4 v4 = *(const float4*)&Vrow[4 * k4];
    vr[4 * k4 + 0] = v4.x; vr[4 * k4 + 1] = v4.y;
    vr[4 * k4 + 2] = v4.z; vr[4 * k4 + 3] = v4.w;
  }
}

// ---------------- pre-split kernels (write d_ws; fragment-order layout) -------
__global__ __launch_bounds__(256) void presplit_w(const float* __restrict__ W,
                                                  unsigned short* __restrict__ Wp) {
  int id = blockIdx.x * 256 + threadIdx.x;
  int row = id & 127;
  int fg = (id >> 7) & 3;
  int mc = id >> 9;
  int mm = mc >> 4, ch = mc & 15;
  const float* src = W + ((size_t)mm * DOUT + row) * DIN + ch * 32 + fg * 8;
  bf16x8 hi, lo;
  unsigned short* hp = (unsigned short*)&hi;
  unsigned short* lp = (unsigned short*)&lo;
#pragma unroll
  for (int e = 0; e < 8; ++e) {
    float v = src[e];
    unsigned short h = f2bf(v);
    hp[e] = h;
    lp[e] = f2bf(v - bf2f(h));
  }
  unsigned short* dst = Wp + (size_t)mc * 8192 + (fg * 128 + row) * 8;
  *(bf16x8*)dst = hi;
  *(bf16x8*)(dst + 4096) = lo;
}

__global__ __launch_bounds__(256) void presplit_x(const float* __restrict__ X,
                                                  unsigned short* __restrict__ Xp) {
  int id = blockIdx.x * 256 + threadIdx.x;
  int col = id & 63;
  int fg = (id >> 6) & 3;
  int bc = id >> 8;
  int bb = bc >> 4, ch = bc & 15;
  const float* src = X + ((size_t)bb * DIN + ch * 32 + fg * 8) * QD + col;
  bf16x8 hi, lo;
  unsigned short* hp = (unsigned short*)&hi;
  unsigned short* lp = (unsigned short*)&lo;
#pragma unroll
  for (int e = 0; e < 8; ++e) {
    float v = src[(size_t)e * QD];
    unsigned short h = f2bf(v);
    hp[e] = h;
    lp[e] = f2bf(v - bf2f(h));
  }
  unsigned short* dst = Xp + (size_t)bc * 4096 + (fg * 64 + col) * 8;
  *(bf16x8*)dst = hi;
  *(bf16x8*)(dst + 2048) = lo;
}

// One block (512 thr = 8 waves) per matrix (m,b). R10 structure + algebraic
// publish-ahead tail (next pivot's norm from pre-update values), all-VALU
// butterfly, and the redundant 2a->2b boundary barrier removed.
template <bool PRE>
__global__ __launch_bounds__(512, 6) void frmap_qr(
    const float* __restrict__ X, const float* __restrict__ W,
    float* __restrict__ out, const unsigned short* __restrict__ Wp,
    const unsigned short* __restrict__ Xp) {
  __shared__ __align__(16) float Buf[64][68];   // stride 68: 2-way max (free)
  __shared__ __align__(16) float Vq[2][8][20];  // conflict-free b128 (R10)
  __shared__ float Tau[QD];

  const int tid = threadIdx.x;
  const int l = tid & 63;
  const int w = __builtin_amdgcn_readfirstlane(tid >> 6);  // wave 0..7
  const int rg = w >> 1;  // GEMM row-group
  const int cg = w & 1;   // GEMM col-group
  const int c = tid >> 3; // QR column 0..63
  const int t = tid & 7;  // QR row class (rows t+8k)
  const int fr = l & 15;
  const int fg = l >> 4;

  const int bid = blockIdx.x;  // m*256 + b
  const int m = bid >> 8;
  const int b = bid & 255;
  const float* Xb = X + (size_t)b * (DIN * QD);
  const float* Wm = W + (size_t)m * (DOUT * DIN);

  f32x4 acc[2][2];
#pragma unroll
  for (int tr = 0; tr < 2; ++tr)
#pragma unroll
    for (int tc = 0; tc < 2; ++tc)
      acc[tr][tc] = (f32x4){0.f, 0.f, 0.f, 0.f};

  if constexpr (PRE) {
    const char* wsrc = (const char*)Wp + (size_t)(m * 16) * 16384;
    const char* xsrc = (const char*)Xp + (size_t)(b * 16) * 8192;
    const int woff = (fg * 128 + 32 * rg + fr) * 16;
    const int xoff = (fg * 64 + 32 * cg + fr) * 16;
    for (int ch = 0; ch < 16; ++ch) {
      bf16x8 ah0 = *(const bf16x8*)(wsrc + woff);
      bf16x8 al0 = *(const bf16x8*)(wsrc + 8192 + woff);
      bf16x8 ah1 = *(const bf16x8*)(wsrc + woff + 256);
      bf16x8 al1 = *(const bf16x8*)(wsrc + 8192 + woff + 256);
      bf16x8 bh0 = *(const bf16x8*)(xsrc + xoff);
      bf16x8 bl0 = *(const bf16x8*)(xsrc + 4096 + xoff);
      bf16x8 bh1 = *(const bf16x8*)(xsrc + xoff + 256);
      bf16x8 bl1 = *(const bf16x8*)(xsrc + 4096 + xoff + 256);
      acc[0][0] = __builtin_amdgcn_mfma_f32_16x16x32_bf16(ah0, bh0, acc[0][0], 0, 0, 0);
      acc[0][0] = __builtin_amdgcn_mfma_f32_16x16x32_bf16(ah0, bl0, acc[0][0], 0, 0, 0);
      acc[0][0] = __builtin_amdgcn_mfma_f32_16x16x32_bf16(al0, bh0, acc[0][0], 0, 0, 0);
      acc[0][1] = __builtin_amdgcn_mfma_f32_16x16x32_bf16(ah0, bh1, acc[0][1], 0, 0, 0);
      acc[0][1] = __builtin_amdgcn_mfma_f32_16x16x32_bf16(ah0, bl1, acc[0][1], 0, 0, 0);
      acc[0][1] = __builtin_amdgcn_mfma_f32_16x16x32_bf16(al0, bh1, acc[0][1], 0, 0, 0);
      acc[1][0] = __builtin_amdgcn_mfma_f32_16x16x32_bf16(ah1, bh0, acc[1][0], 0, 0, 0);
      acc[1][0] = __builtin_amdgcn_mfma_f32_16x16x32_bf16(ah1, bl0, acc[1][0], 0, 0, 0);
      acc[1][0] = __builtin_amdgcn_mfma_f32_16x16x32_bf16(al1, bh0, acc[1][0], 0, 0, 0);
      acc[1][1] = __builtin_amdgcn_mfma_f32_16x16x32_bf16(ah1, bh1, acc[1][1], 0, 0, 0);
      acc[1][1] = __builtin_amdgcn_mfma_f32_16x16x32_bf16(ah1, bl1, acc[1][1], 0, 0, 0);
      acc[1][1] = __builtin_amdgcn_mfma_f32_16x16x32_bf16(al1, bh1, acc[1][1], 0, 0, 0);
      wsrc += 16384;
      xsrc += 8192;
    }
  } else {
    for (int ch = 0; ch < 16; ++ch) {
      int kc = ch * 32;
      bf16x8 ah[2], al[2], bh[2], bl[2];
#pragma unroll
      for (int tr = 0; tr < 2; ++tr) {
        const float* ws = Wm + (size_t)(32 * rg + 16 * tr + fr) * DIN + kc + 8 * fg;
        float4 v0 = *(const float4*)ws;
        float4 v1 = *(const float4*)(ws + 4);
        float p[8] = {v0.x, v0.y, v0.z, v0.w, v1.x, v1.y, v1.z, v1.w};
        unsigned short* hp = (unsigned short*)&ah[tr];
        unsigned short* lp = (unsigned short*)&al[tr];
#pragma unroll
        for (int e = 0; e < 8; ++e) {
          unsigned short h = f2bf(p[e]);
          hp[e] = h;
          lp[e] = f2bf(p[e] - bf2f(h));
        }
      }
#pragma unroll
      for (int tc = 0; tc < 2; ++tc) {
        const float* xs = Xb + (size_t)(kc + 8 * fg) * QD + 32 * cg + 16 * tc + fr;
        unsigned short* hp = (unsigned short*)&bh[tc];
        unsigned short* lp = (unsigned short*)&bl[tc];
#pragma unroll
        for (int e = 0; e < 8; ++e) {
          float v = xs[(size_t)e * QD];
          unsigned short h = f2bf(v);
          hp[e] = h;
          lp[e] = f2bf(v - bf2f(h));
        }
      }
#pragma unroll
      for (int tr = 0; tr < 2; ++tr)
#pragma unroll
        for (int tc = 0; tc < 2; ++tc) {
          acc[tr][tc] = __builtin_amdgcn_mfma_f32_16x16x32_bf16(ah[tr], bh[tc], acc[tr][tc], 0, 0, 0);
          acc[tr][tc] = __builtin_amdgcn_mfma_f32_16x16x32_bf16(ah[tr], bl[tc], acc[tr][tc], 0, 0, 0);
          acc[tr][tc] = __builtin_amdgcn_mfma_f32_16x16x32_bf16(al[tr], bh[tc], acc[tr][tc], 0, 0, 0);
        }
    }
  }

  // ---------------- Phase 1.5: acc -> Buf -> QR ownership (R10)
  float a[16];
  if (rg < 2) {  // rows 0..63
#pragma unroll
    for (int tr = 0; tr < 2; ++tr)
#pragma unroll
      for (int tc = 0; tc < 2; ++tc)
#pragma unroll
        for (int v = 0; v < 4; ++v)
          Buf[32 * rg + 16 * tr + 4 * fg + v][32 * cg + 16 * tc + fr] = acc[tr][tc][v];
  }
  __syncthreads();
#pragma unroll
  for (int k = 0; k < 8; ++k) a[k] = Buf[t + 8 * k][c];
  __syncthreads();
  if (rg >= 2) {  // rows 64..127
#pragma unroll
    for (int tr = 0; tr < 2; ++tr)
#pragma unroll
      for (int tc = 0; tc < 2; ++tc)
#pragma unroll
        for (int v = 0; v < 4; ++v)
          Buf[32 * (rg - 2) + 16 * tr + 4 * fg + v][32 * cg + 16 * tc + fr] = acc[tr][tc][v];
  }
  __syncthreads();
#pragma unroll
  for (int k = 8; k < 16; ++k) a[k] = Buf[t + 8 * k - 64][c];

  // ---------------- prologue: group c==0 makes tau0/invs0, scales, publishes
  if (c == 0) {
    float myalpha = 0.f;
#pragma unroll
    for (int k = 0; k < 16; ++k)
      if (t + 8 * k == 0) myalpha = a[k];
    float xn2 = groupSum8(tree_norm_gt16(a, t, 0));
    float alpha = groupSum8(myalpha);  // exact: zeros elsewhere
    float tau, invs;
    make_tau(xn2, alpha, tau, invs);
    if (t == 0) Tau[0] = tau;
    publish_col16<true>(a, t, 0, invs, &Vq[0][t][0]);
  }
  __syncthreads();  // B0: V_0 / Tau[0] visible

  // ---------------- Phase 2a: sgeqr2 (1 barrier/step, algebraic tail)
  for (int j = 0; j < QD - 1; ++j) {
    if (c > j) {
      float taul = Tau[j];
      float vr[16];
      load_v16(vr, &Vq[j & 1][t][0]);
      float pd = tree_dot16(vr, a);
      if (c == j + 1) {
        // Tail: next pivot's norm/alpha from PRE-update values (concurrent
        // with the dot butterfly) — removes update->norm from the barrier
        // critical path. Identity: ||a - w v||^2 = Saa - 2w Sav + w^2 Svv.
        float saa4[4] = {0.f, 0.f, 0.f, 0.f};
        float svv4[4] = {0.f, 0.f, 0.f, 0.f};
        float corr = 0.f, vcor = 0.f, A1 = 0.f, V1 = 0.f;
#pragma unroll
        for (int q = 0; q < 4; ++q)
#pragma unroll
          for (int kk = 0; kk < 4; ++kk) {
            int k = 4 * q + kk;
            int r = t + 8 * k;
            float av = a[k], vv = vr[k];
            if (r > j + 1) saa4[q] = fmaf(av, av, saa4[q]);
            svv4[q] = fmaf(vv, vv, svv4[q]);
            if (r == j) corr += av;  // vr_j == 1
            if (r == j + 1) {
              corr = fmaf(vv, av, corr);
              vcor = fmaf(vv, vv, vcor);
              A1 += av;
              V1 += vv;
            }
          }
        float psum = groupSum8(pd);
        float wv = taul * psum;
        float S_aa = groupSum8(((saa4[0] + saa4[1]) + saa4[2]) + saa4[3]);
        float Svvr = groupSum8(((svv4[0] + svv4[1]) + svv4[2]) + svv4[3]);
        float C = groupSum8(corr);
        float VC = groupSum8(vcor);
        float A1s = groupSum8(A1);
        float V1s = groupSum8(V1);
        float S_av = psum - C;
        float S_vv = (Svvr - 1.f) - VC;
        float xn2 = fmaxf(fmaf(wv, fmaf(wv, S_vv, -2.f * S_av), S_aa), 0.f);
        float alpha = fmaf(-wv, V1s, A1s);
        float tau, invs;
        make_tau(xn2, alpha, tau, invs);
        if (t == 0) Tau[j + 1] = tau;
        // fused update + scale + publish
#pragma unroll
        for (int k4 = 0; k4 < 4; ++k4) {
          float4 v4;
          float* vvp = (float*)&v4;
#pragma unroll
          for (int e = 0; e < 4; ++e) {
            int k = 4 * k4 + e;
            int r = t + 8 * k;
            float av = fmaf(-wv, vr[k], a[k]);
            float nv;
            if (r > j + 1) { av *= invs; nv = av; }
            else nv = (r == j + 1) ? 1.f : 0.f;
            a[k] = av;
            vvp[e] = nv;
          }
          *(float4*)&Vq[(j + 1) & 1][t][4 * k4] = v4;
        }
      } else {
        float wv = taul * groupSum8(pd);
#pragma unroll
        for (int k = 0; k < 16; ++k) a[k] = fmaf(-wv, vr[k], a[k]);
      }
    }
    __syncthreads();  // fences V_{j+1}, Tau[j+1], Vq buffer reuse
  }
  // (boundary barrier removed: j=62's end barrier already fences Vq/Tau)

  // ---------------- Phase 2b: sorg2r (1 barrier/step, publish-ahead) — R10
  for (int i = QD - 1; i >= 0; --i) {
    if (c > i) {
      float taul = Tau[i];
      float vr[16];
      load_v16(vr, &Vq[i & 1][t][0]);
      float wv = taul * groupSum8(tree_dot16(vr, a));
#pragma unroll
      for (int k = 0; k < 16; ++k) a[k] = fmaf(-wv, vr[k], a[k]);
    } else if (c == i) {  // own column: 0 / 1-tau / -tau*v
      float taul = Tau[i];
#pragma unroll
      for (int k = 0; k < 16; ++k) {
        int r = t + 8 * k;
        float val = a[k];
        float nv;
        if (r == i) nv = 1.f - taul;
        else if (r < i) nv = 0.f;
        else nv = -taul * val;
        a[k] = nv;
      }
    } else if (c == i - 1) {  // idle group publishes V_{i-1}
      publish_col16<false>(a, t, i - 1, 0.f, &Vq[(i - 1) & 1][t][0]);
    }
    if (i) __syncthreads();
  }

  // ---------------- Phase 3: store via Buf (256B-coalesced) — R10
  float* O = out + (size_t)bid * (DOUT * QD);
#pragma unroll
  for (int k = 0; k < 8; ++k) Buf[t + 8 * k][c] = a[k];
  __syncthreads();
#pragma unroll
  for (int i = 0; i < 8; ++i) {
    int r = 8 * w + i;
    O[r * QD + l] = Buf[r][l];
  }
  __syncthreads();
#pragma unroll
  for (int k = 8; k < 16; ++k) Buf[t + 8 * k - 64][c] = a[k];
  __syncthreads();
#pragma unroll
  for (int i = 0; i < 8; ++i) {
    int r = 8 * w + i;
    O[(64 + r) * QD + l] = Buf[r][l];
  }
}

extern "C" void kernel_launch(void* const* d_in, const int* in_sizes, int n_in,
                              void* d_out, int out_size, void* d_ws, size_t ws_size,
                              hipStream_t stream) {
  const float* X = (const float*)d_in[0];   // (256, 512, 64) fp32
  const float* W = (const float*)d_in[1];   // (16, 128, 512) fp32
  float* out = (float*)d_out;               // (4096, 128, 64) fp32

  const size_t needW = (size_t)NMAPS * 16 * 16384;  // 4 MiB
  const size_t needX = (size_t)256 * 16 * 8192;     // 32 MiB
  if (ws_size >= needW + needX) {
    unsigned short* Wp = (unsigned short*)d_ws;
    unsigned short* Xp = (unsigned short*)((char*)d_ws + needW);
    presplit_w<<<512, 256, 0, stream>>>(W, Wp);
    presplit_x<<<4096, 256, 0, stream>>>(X, Xp);
    frmap_qr<true><<<NMAPS * 256, 512, 0, stream>>>(X, W, out, Wp, Xp);
  } else {
    frmap_qr<false><<<NMAPS * 256, 512, 0, stream>>>(X, W, out, nullptr, nullptr);
  }
}

// Round 13
// 379.312 us; speedup vs baseline: 1.5482x; 1.5482x over previous
//
#include <hip/hip_runtime.h>
#include <math.h>

#define NMAPS 16
#define DIN 512
#define DOUT 128
#define QD 64

typedef __attribute__((ext_vector_type(8))) short bf16x8;  // 8 bf16 (4 VGPR)
typedef __attribute__((ext_vector_type(4))) float f32x4;
typedef __attribute__((ext_vector_type(2))) float f32x2;

// Packed fp32 FMA (VOP3P): d = a*b + c elementwise on a 2-wide f32 pair.
// Bitwise-identical to two scalar fmaf's; halves VALU issue on the hot path.
__device__ __forceinline__ f32x2 pkfma(f32x2 a, f32x2 b, f32x2 c) {
  f32x2 d;
  asm("v_pk_fma_f32 %0, %1, %2, %3" : "=v"(d) : "v"(a), "v"(b), "v"(c));
  return d;
}

// bf16 split helpers (RNE). x = bf2f(hi) + bf2f(lo) + O(2^-18 |x|).
__device__ __forceinline__ unsigned short f2bf(float x) {
  unsigned int u = __float_as_uint(x);
  return (unsigned short)((u + 0x7FFFu + ((u >> 16) & 1u)) >> 16);
}
__device__ __forceinline__ float bf2f(unsigned short h) {
  return __uint_as_float(((unsigned int)h) << 16);
}

// DPP helpers (VALU pipe).
__device__ __forceinline__ float qxor1(float x) {  // quad_perm {1,0,3,2}
  return __int_as_float(__builtin_amdgcn_update_dpp(
      0, __float_as_int(x), 0xB1, 0xF, 0xF, true));
}
__device__ __forceinline__ float qxor2(float x) {  // quad_perm {2,3,0,1}
  return __int_as_float(__builtin_amdgcn_update_dpp(
      0, __float_as_int(x), 0x4E, 0xF, 0xF, true));
}
__device__ __forceinline__ float hmirror(float x) {  // row_half_mirror: l->7-l
  return __int_as_float(__builtin_amdgcn_update_dpp(
      0, __float_as_int(x), 0x141, 0xF, 0xF, true));
}
// Butterfly sum over the 8-lane group, all-VALU (no LDS). Bitwise-identical
// to the ds_swizzle xor-4 version: after qxor1+qxor2 the value is
// quad-uniform; half-mirror pairs each lane with the other quad.
__device__ __forceinline__ float groupSum8(float x) {
  x += qxor1(x);
  x += qxor2(x);
  x += hmirror(x);
  return x;
}

// slarfg sign convention (LAPACK) — unchanged since R4.
__device__ __forceinline__ void make_tau(float xn2, float alpha, float& tau,
                                         float& invs) {
  if (xn2 == 0.f) { tau = 0.f; invs = 0.f; }
  else {
    float mag = sqrtf(alpha * alpha + xn2);
    float beta = (alpha >= 0.f) ? -mag : mag;
    tau = (beta - alpha) / beta;
    invs = 1.f / (alpha - beta);
  }
}

// Packed dot over 16 elements: 8 pk_fma (4 chains of 4) + ordered combine.
__device__ __forceinline__ float pk_dot8(const f32x2 (&x)[8],
                                         const f32x2 (&y)[8]) {
  f32x2 pa = {0.f, 0.f}, pb = {0.f, 0.f};
#pragma unroll
  for (int i = 0; i < 4; ++i) {
    pa = pkfma(x[2 * i], y[2 * i], pa);
    pb = pkfma(x[2 * i + 1], y[2 * i + 1], pb);
  }
  return (pa.x + pa.y) + (pb.x + pb.y);
}

// Masked norm^2 over rows r = t+8k > piv (tail/prologue group only).
__device__ __forceinline__ float norm_gt8(const f32x2 (&a2)[8], const int t,
                                          const int piv) {
  float ss[4] = {0.f, 0.f, 0.f, 0.f};
#pragma unroll
  for (int q = 0; q < 4; ++q)
#pragma unroll
    for (int kk = 0; kk < 4; ++kk) {
      int k = 4 * q + kk;
      int r = t + 8 * k;
      float av = a2[k >> 1][k & 1];  // constant indices after unroll
      if (r > piv) ss[q] = fmaf(av, av, ss[q]);
    }
  return ((ss[0] + ss[1]) + ss[2]) + ss[3];
}

template <bool SCALE>
__device__ __forceinline__ void publish_col8(f32x2 (&a2)[8], const int t,
                                             const int piv, const float invs,
                                             float* __restrict__ Vrow) {
#pragma unroll
  for (int k4 = 0; k4 < 4; ++k4) {
    float4 v4;
    float* vv = (float*)&v4;
#pragma unroll
    for (int e = 0; e < 4; ++e) {
      int k = 4 * k4 + e;
      int r = t + 8 * k;
      float av = a2[k >> 1][k & 1];
      float nv;
      if (r > piv) {
        if (SCALE) { av *= invs; a2[k >> 1][k & 1] = av; }
        nv = av;
      } else nv = (r == piv) ? 1.f : 0.f;
      vv[e] = nv;
    }
    *(float4*)&Vrow[4 * k4] = v4;
  }
}

__device__ __forceinline__ void load_v8(f32x2 (&vr2)[8],
                                        const float* __restrict__ Vrow) {
#pragma unroll
  for (int k4 = 0; k4 < 4; ++k4) {
    float4 v4 = *(const float4*)&Vrow[4 * k4];
    vr2[2 * k4] = (f32x2){v4.x, v4.y};
    vr2[2 * k4 + 1] = (f32x2){v4.z, v4.w};
  }
}

// ---------------- pre-split kernels (write d_ws; fragment-order layout) -------
__global__ __launch_bounds__(256) void presplit_w(const float* __restrict__ W,
                                                  unsigned short* __restrict__ Wp) {
  int id = blockIdx.x * 256 + threadIdx.x;
  int row = id & 127;
  int fg = (id >> 7) & 3;
  int mc = id >> 9;
  int mm = mc >> 4, ch = mc & 15;
  const float* src = W + ((size_t)mm * DOUT + row) * DIN + ch * 32 + fg * 8;
  bf16x8 hi, lo;
  unsigned short* hp = (unsigned short*)&hi;
  unsigned short* lp = (unsigned short*)&lo;
#pragma unroll
  for (int e = 0; e < 8; ++e) {
    float v = src[e];
    unsigned short h = f2bf(v);
    hp[e] = h;
    lp[e] = f2bf(v - bf2f(h));
  }
  unsigned short* dst = Wp + (size_t)mc * 8192 + (fg * 128 + row) * 8;
  *(bf16x8*)dst = hi;
  *(bf16x8*)(dst + 4096) = lo;
}

__global__ __launch_bounds__(256) void presplit_x(const float* __restrict__ X,
                                                  unsigned short* __restrict__ Xp) {
  int id = blockIdx.x * 256 + threadIdx.x;
  int col = id & 63;
  int fg = (id >> 6) & 3;
  int bc = id >> 8;
  int bb = bc >> 4, ch = bc & 15;
  const float* src = X + ((size_t)bb * DIN + ch * 32 + fg * 8) * QD + col;
  bf16x8 hi, lo;
  unsigned short* hp = (unsigned short*)&hi;
  unsigned short* lp = (unsigned short*)&lo;
#pragma unroll
  for (int e = 0; e < 8; ++e) {
    float v = src[(size_t)e * QD];
    unsigned short h = f2bf(v);
    hp[e] = h;
    lp[e] = f2bf(v - bf2f(h));
  }
  unsigned short* dst = Xp + (size_t)bc * 4096 + (fg * 64 + col) * 8;
  *(bf16x8*)dst = hi;
  *(bf16x8*)(dst + 2048) = lo;
}

// One block (512 thr = 8 waves) per matrix (m,b). R10 structure exactly, with
// (a) QR state packed as f32x2[8] and hot dot/update via v_pk_fma_f32
//     (halves hot-path VALU issue; elementwise-identical values), and
// (b) all-VALU butterfly (hmirror instead of ds_swizzle).
template <bool PRE>
__global__ __launch_bounds__(512, 6) void frmap_qr(
    const float* __restrict__ X, const float* __restrict__ W,
    float* __restrict__ out, const unsigned short* __restrict__ Wp,
    const unsigned short* __restrict__ Xp) {
  __shared__ __align__(16) float Buf[64][68];   // stride 68: 2-way max (free)
  __shared__ __align__(16) float Vq[2][8][20];  // conflict-free b128 (R10)
  __shared__ float Tau[QD];

  const int tid = threadIdx.x;
  const int l = tid & 63;
  const int w = __builtin_amdgcn_readfirstlane(tid >> 6);  // wave 0..7
  const int rg = w >> 1;  // GEMM row-group
  const int cg = w & 1;   // GEMM col-group
  const int c = tid >> 3; // QR column 0..63
  const int t = tid & 7;  // QR row class (rows t+8k)
  const int fr = l & 15;
  const int fg = l >> 4;

  const int bid = blockIdx.x;  // m*256 + b
  const int m = bid >> 8;
  const int b = bid & 255;
  const float* Xb = X + (size_t)b * (DIN * QD);
  const float* Wm = W + (size_t)m * (DOUT * DIN);

  f32x4 acc[2][2];
#pragma unroll
  for (int tr = 0; tr < 2; ++tr)
#pragma unroll
    for (int tc = 0; tc < 2; ++tc)
      acc[tr][tc] = (f32x4){0.f, 0.f, 0.f, 0.f};

  if constexpr (PRE) {
    const char* wsrc = (const char*)Wp + (size_t)(m * 16) * 16384;
    const char* xsrc = (const char*)Xp + (size_t)(b * 16) * 8192;
    const int woff = (fg * 128 + 32 * rg + fr) * 16;
    const int xoff = (fg * 64 + 32 * cg + fr) * 16;
    for (int ch = 0; ch < 16; ++ch) {
      bf16x8 ah0 = *(const bf16x8*)(wsrc + woff);
      bf16x8 al0 = *(const bf16x8*)(wsrc + 8192 + woff);
      bf16x8 ah1 = *(const bf16x8*)(wsrc + woff + 256);
      bf16x8 al1 = *(const bf16x8*)(wsrc + 8192 + woff + 256);
      bf16x8 bh0 = *(const bf16x8*)(xsrc + xoff);
      bf16x8 bl0 = *(const bf16x8*)(xsrc + 4096 + xoff);
      bf16x8 bh1 = *(const bf16x8*)(xsrc + xoff + 256);
      bf16x8 bl1 = *(const bf16x8*)(xsrc + 4096 + xoff + 256);
      acc[0][0] = __builtin_amdgcn_mfma_f32_16x16x32_bf16(ah0, bh0, acc[0][0], 0, 0, 0);
      acc[0][0] = __builtin_amdgcn_mfma_f32_16x16x32_bf16(ah0, bl0, acc[0][0], 0, 0, 0);
      acc[0][0] = __builtin_amdgcn_mfma_f32_16x16x32_bf16(al0, bh0, acc[0][0], 0, 0, 0);
      acc[0][1] = __builtin_amdgcn_mfma_f32_16x16x32_bf16(ah0, bh1, acc[0][1], 0, 0, 0);
      acc[0][1] = __builtin_amdgcn_mfma_f32_16x16x32_bf16(ah0, bl1, acc[0][1], 0, 0, 0);
      acc[0][1] = __builtin_amdgcn_mfma_f32_16x16x32_bf16(al0, bh1, acc[0][1], 0, 0, 0);
      acc[1][0] = __builtin_amdgcn_mfma_f32_16x16x32_bf16(ah1, bh0, acc[1][0], 0, 0, 0);
      acc[1][0] = __builtin_amdgcn_mfma_f32_16x16x32_bf16(ah1, bl0, acc[1][0], 0, 0, 0);
      acc[1][0] = __builtin_amdgcn_mfma_f32_16x16x32_bf16(al1, bh0, acc[1][0], 0, 0, 0);
      acc[1][1] = __builtin_amdgcn_mfma_f32_16x16x32_bf16(ah1, bh1, acc[1][1], 0, 0, 0);
      acc[1][1] = __builtin_amdgcn_mfma_f32_16x16x32_bf16(ah1, bl1, acc[1][1], 0, 0, 0);
      acc[1][1] = __builtin_amdgcn_mfma_f32_16x16x32_bf16(al1, bh1, acc[1][1], 0, 0, 0);
      wsrc += 16384;
      xsrc += 8192;
    }
  } else {
    for (int ch = 0; ch < 16; ++ch) {
      int kc = ch * 32;
      bf16x8 ah[2], al[2], bh[2], bl[2];
#pragma unroll
      for (int tr = 0; tr < 2; ++tr) {
        const float* ws = Wm + (size_t)(32 * rg + 16 * tr + fr) * DIN + kc + 8 * fg;
        float4 v0 = *(const float4*)ws;
        float4 v1 = *(const float4*)(ws + 4);
        float p[8] = {v0.x, v0.y, v0.z, v0.w, v1.x, v1.y, v1.z, v1.w};
        unsigned short* hp = (unsigned short*)&ah[tr];
        unsigned short* lp = (unsigned short*)&al[tr];
#pragma unroll
        for (int e = 0; e < 8; ++e) {
          unsigned short h = f2bf(p[e]);
          hp[e] = h;
          lp[e] = f2bf(p[e] - bf2f(h));
        }
      }
#pragma unroll
      for (int tc = 0; tc < 2; ++tc) {
        const float* xs = Xb + (size_t)(kc + 8 * fg) * QD + 32 * cg + 16 * tc + fr;
        unsigned short* hp = (unsigned short*)&bh[tc];
        unsigned short* lp = (unsigned short*)&bl[tc];
#pragma unroll
        for (int e = 0; e < 8; ++e) {
          float v = xs[(size_t)e * QD];
          unsigned short h = f2bf(v);
          hp[e] = h;
          lp[e] = f2bf(v - bf2f(h));
        }
      }
#pragma unroll
      for (int tr = 0; tr < 2; ++tr)
#pragma unroll
        for (int tc = 0; tc < 2; ++tc) {
          acc[tr][tc] = __builtin_amdgcn_mfma_f32_16x16x32_bf16(ah[tr], bh[tc], acc[tr][tc], 0, 0, 0);
          acc[tr][tc] = __builtin_amdgcn_mfma_f32_16x16x32_bf16(ah[tr], bl[tc], acc[tr][tc], 0, 0, 0);
          acc[tr][tc] = __builtin_amdgcn_mfma_f32_16x16x32_bf16(al[tr], bh[tc], acc[tr][tc], 0, 0, 0);
        }
    }
  }

  // ---------------- Phase 1.5: acc -> Buf -> QR ownership (R10)
  f32x2 a2[8];
  if (rg < 2) {  // rows 0..63
#pragma unroll
    for (int tr = 0; tr < 2; ++tr)
#pragma unroll
      for (int tc = 0; tc < 2; ++tc)
#pragma unroll
        for (int v = 0; v < 4; ++v)
          Buf[32 * rg + 16 * tr + 4 * fg + v][32 * cg + 16 * tc + fr] = acc[tr][tc][v];
  }
  __syncthreads();
#pragma unroll
  for (int k = 0; k < 8; ++k) a2[k >> 1][k & 1] = Buf[t + 8 * k][c];
  __syncthreads();
  if (rg >= 2) {  // rows 64..127
#pragma unroll
    for (int tr = 0; tr < 2; ++tr)
#pragma unroll
      for (int tc = 0; tc < 2; ++tc)
#pragma unroll
        for (int v = 0; v < 4; ++v)
          Buf[32 * (rg - 2) + 16 * tr + 4 * fg + v][32 * cg + 16 * tc + fr] = acc[tr][tc][v];
  }
  __syncthreads();
#pragma unroll
  for (int k = 8; k < 16; ++k) a2[k >> 1][k & 1] = Buf[t + 8 * k - 64][c];

  // ---------------- prologue: group c==0 makes tau0/invs0, scales, publishes
  if (c == 0) {
    float myalpha = 0.f;
#pragma unroll
    for (int k = 0; k < 16; ++k)
      if (t + 8 * k == 0) myalpha = a2[k >> 1][k & 1];
    float xn2 = groupSum8(norm_gt8(a2, t, 0));
    float alpha = groupSum8(myalpha);  // exact: zeros elsewhere
    float tau, invs;
    make_tau(xn2, alpha, tau, invs);
    if (t == 0) Tau[0] = tau;
    publish_col8<true>(a2, t, 0, invs, &Vq[0][t][0]);
  }
  __syncthreads();  // B0: V_0 / Tau[0] visible

  // ---------------- Phase 2a: sgeqr2 (1 barrier/step, publish-ahead) — R10
  for (int j = 0; j < QD - 1; ++j) {
    if (c > j) {
      float taul = Tau[j];
      f32x2 vr2[8];
      load_v8(vr2, &Vq[j & 1][t][0]);
      float wv = taul * groupSum8(pk_dot8(vr2, a2));
      f32x2 nw2 = {-wv, -wv};
#pragma unroll
      for (int i = 0; i < 8; ++i) a2[i] = pkfma(nw2, vr2[i], a2[i]);
      if (c == j + 1) {  // tail: next pivot's tau/scale/publish (R10 form)
        float myalpha = 0.f;
#pragma unroll
        for (int k = 0; k < 16; ++k)
          if (t + 8 * k == j + 1) myalpha = a2[k >> 1][k & 1];
        float xn2 = groupSum8(norm_gt8(a2, t, j + 1));
        float alpha = groupSum8(myalpha);
        float tau, invs;
        make_tau(xn2, alpha, tau, invs);
        if (t == 0) Tau[j + 1] = tau;
        publish_col8<true>(a2, t, j + 1, invs, &Vq[(j + 1) & 1][t][0]);
      }
    }
    __syncthreads();  // fences V_{j+1}, Tau[j+1], Vq buffer reuse
  }

  __syncthreads();  // phase boundary (R10)

  // ---------------- Phase 2b: sorg2r (1 barrier/step, publish-ahead) — R10
  for (int i = QD - 1; i >= 0; --i) {
    if (c > i) {
      float taul = Tau[i];
      f32x2 vr2[8];
      load_v8(vr2, &Vq[i & 1][t][0]);
      float wv = taul * groupSum8(pk_dot8(vr2, a2));
      f32x2 nw2 = {-wv, -wv};
#pragma unroll
      for (int q = 0; q < 8; ++q) a2[q] = pkfma(nw2, vr2[q], a2[q]);
    } else if (c == i) {  // own column: 0 / 1-tau / -tau*v
      float taul = Tau[i];
#pragma unroll
      for (int k = 0; k < 16; ++k) {
        int r = t + 8 * k;
        float val = a2[k >> 1][k & 1];
        float nv;
        if (r == i) nv = 1.f - taul;
        else if (r < i) nv = 0.f;
        else nv = -taul * val;
        a2[k >> 1][k & 1] = nv;
      }
    } else if (c == i - 1) {  // idle group publishes V_{i-1}
      publish_col8<false>(a2, t, i - 1, 0.f, &Vq[(i - 1) & 1][t][0]);
    }
    if (i) __syncthreads();
  }

  // ---------------- Phase 3: store via Buf (256B-coalesced) — R10
  float* O = out + (size_t)bid * (DOUT * QD);
#pragma unroll
  for (int k = 0; k < 8; ++k) Buf[t + 8 * k][c] = a2[k >> 1][k & 1];
  __syncthreads();
#pragma unroll
  for (int i = 0; i < 8; ++i) {
    int r = 8 * w + i;
    O[r * QD + l] = Buf[r][l];
  }
  __syncthreads();
#pragma unroll
  for (int k = 8; k < 16; ++k) Buf[t + 8 * k - 64][c] = a2[k >> 1][k & 1];
  __syncthreads();
#pragma unroll
  for (int i = 0; i < 8; ++i) {
    int r = 8 * w + i;
    O[(64 + r) * QD + l] = Buf[r][l];
  }
}

extern "C" void kernel_launch(void* const* d_in, const int* in_sizes, int n_in,
                              void* d_out, int out_size, void* d_ws, size_t ws_size,
                              hipStream_t stream) {
  const float* X = (const float*)d_in[0];   // (256, 512, 64) fp32
  const float* W = (const float*)d_in[1];   // (16, 128, 512) fp32
  float* out = (float*)d_out;               // (4096, 128, 64) fp32

  const size_t needW = (size_t)NMAPS * 16 * 16384;  // 4 MiB
  const size_t needX = (size_t)256 * 16 * 8192;     // 32 MiB
  if (ws_size >= needW + needX) {
    unsigned short* Wp = (unsigned short*)d_ws;
    unsigned short* Xp = (unsigned short*)((char*)d_ws + needW);
    presplit_w<<<512, 256, 0, stream>>>(W, Wp);
    presplit_x<<<4096, 256, 0, stream>>>(X, Xp);
    frmap_qr<true><<<NMAPS * 256, 512, 0, stream>>>(X, W, out, Wp, Xp);
  } else {
    frmap_qr<false><<<NMAPS * 256, 512, 0, stream>>>(X, W, out, nullptr, nullptr);
  }
}